// Round 4
// baseline (158.201 us; speedup 1.0000x reference)
//
#include <hip/hip_runtime.h>
#include <hip/hip_fp16.h>

// FourierFilter: out = Re(IFFT(mask * FFT(x, axis=-1))), mask zeroes bins with
// |freq| < 10 Hz (kf <= 819 of 8192 @ 100 Hz). x: [64,128,8192] f32.
//
// Register-resident four-step FFT. Two real rows packed into one complex row.
// 256 threads x 32 float2 regs. Radix-2 DIF stage spans decomposed 5+5+3:
//   phase1 (regs): spans 4096..256 on {c + 256m}  = const-twiddle FFT32 + post
//                  twiddle W_8192^{c*brev5(m)} (block-uniform deferral).
//   phase2 (regs): spans 128..8 on {256*blk + off3 + 8m}, c' = 32*off3.
//   phase3 (regs): contiguous FFT8s: fwd + MASK(brev13) + inv fused, no LDS.
//   inverse mirrors (conj pre-twiddle, then DIT).
// 4 LDS round-trips / 4 barriers (each thread's phase read-set == write-set).
//
// R3 change: LDS intermediates in fp16 (__half2 packs re/im -> 4B/elem):
//   z-array 64KB -> 32.5KB  => 4 blocks/CU (was 2), LDS traffic halved.
//   fp16 u=2^-11 at 4 quantization events: ~+5e-3 absmax (threshold 0.1025).
// Pad phys(n)=n+(n>>6) with 4B elems: all phase patterns exactly 2 lanes/bank
// (2-way is free on wave64).

#define FFT_N 8192
#define NT    256
#define PHY(i) ((i) + ((i) >> 6))

__device__ __forceinline__ float2 cadd(float2 a, float2 b){ return make_float2(a.x+b.x, a.y+b.y); }
__device__ __forceinline__ float2 csub(float2 a, float2 b){ return make_float2(a.x-b.x, a.y-b.y); }
__device__ __forceinline__ float2 cmul(float2 a, float2 b){
    return make_float2(fmaf(a.x, b.x, -(a.y*b.y)), fmaf(a.x, b.y, a.y*b.x));
}

// d * W_32^j (or conj), j in [0,16), compile-time after unroll -> branches fold.
__device__ __forceinline__ float2 mul_w32(float2 d, int j, bool cj){
  if (j == 0) return d;
  if (j == 8) return cj ? make_float2(-d.y, d.x) : make_float2(d.y, -d.x);
  const float C[16] = {1.f, 0.98078528f, 0.92387953f, 0.83146961f, 0.70710678f,
                       0.55557023f, 0.38268343f, 0.19509032f, 0.f, -0.19509032f,
                       -0.38268343f, -0.55557023f, -0.70710678f, -0.83146961f,
                       -0.92387953f, -0.98078528f};
  const float S[16] = {0.f, -0.19509032f, -0.38268343f, -0.55557023f, -0.70710678f,
                       -0.83146961f, -0.92387953f, -0.98078528f, -1.f, -0.98078528f,
                       -0.92387953f, -0.83146961f, -0.70710678f, -0.55557023f,
                       -0.38268343f, -0.19509032f};
  return cmul(d, make_float2(C[j], cj ? -S[j] : S[j]));
}

// DIF radix-2 stages, spans L..1 over SZ regs. Twiddle W_SZ^{j*(SZ/2/L)} == W_32^{j*16/L}.
template<int SZ, int L>
__device__ __forceinline__ void dif_rec(float2* r){
  #pragma unroll
  for (int g = 0; g < SZ; g += 2*L){
    #pragma unroll
    for (int j = 0; j < L; ++j){
      float2 u = r[g+j], v = r[g+j+L];
      r[g+j]   = cadd(u, v);
      r[g+j+L] = mul_w32(csub(u, v), j*(16/L), false);
    }
  }
  if constexpr (L > 1) dif_rec<SZ, L/2>(r);
}

// Inverse DIT radix-2 stages, spans 1..SZ/2 (conjugate twiddles), unnormalized.
template<int SZ, int L>
__device__ __forceinline__ void dit_rec(float2* r){
  #pragma unroll
  for (int g = 0; g < SZ; g += 2*L){
    #pragma unroll
    for (int j = 0; j < L; ++j){
      float2 a = r[g+j];
      float2 b = mul_w32(r[g+j+L], j*(16/L), true);
      r[g+j]   = cadd(a, b);
      r[g+j+L] = csub(a, b);
    }
  }
  if constexpr (2*L < SZ) dit_rec<SZ, 2*L>(r);
}

__host__ __device__ constexpr int brev5(int k){
  return ((k&1)<<4) | ((k&2)<<2) | (k&4) | ((k&8)>>2) | ((k&16)>>4);
}

// r[brev5(k)] *= W_8192^{cbase*k} (or conj), k=1..31, via 1 sincos + power chain.
__device__ __forceinline__ void twiddle_scale(float2* r, int cbase, bool cj){
  float s, c;
  __sincosf((float)cbase * -7.6699039394282061e-4f, &s, &c);  // -2*pi/8192
  if (cj) s = -s;
  const float2 w1 = make_float2(c, s);
  float2 w = w1;
  r[brev5(1)] = cmul(r[brev5(1)], w);
  #pragma unroll
  for (int k = 2; k < 32; ++k){
    w = cmul(w, w1);
    r[brev5(k)] = cmul(r[brev5(k)], w);
  }
}

__global__ __launch_bounds__(NT, 4)
void fourier_filter_kernel(const float* __restrict__ x, float* __restrict__ out){
  __shared__ __half2 zs[FFT_N + FFT_N/64];   // 8320 * 4B = 32.5 KB (pad every 64)
  const int t = threadIdx.x;
  const long long pair = blockIdx.x;
  const float* r0 = x + pair * (2LL * FFT_N);
  const float* r1 = r0 + FFT_N;
  float2 r[32];

  // ---- fwd phase 1: spans 4096..256 on {t + 256m} (coalesced global load) ----
  #pragma unroll
  for (int m = 0; m < 32; ++m){
    const int n = t + (m << 8);
    r[m] = make_float2(__builtin_nontemporal_load(r0 + n),
                       __builtin_nontemporal_load(r1 + n));
  }
  dif_rec<32, 16>(r);
  twiddle_scale(r, t, false);
  #pragma unroll
  for (int m = 0; m < 32; ++m)
    zs[PHY(t + (m<<8))] = __floats2half2_rn(r[m].x, r[m].y);
  __syncthreads();

  // ---- fwd phase 2: spans 128..8 on {256*(t>>3) + (t&7) + 8m} ----
  const int base2 = ((t >> 3) << 8) | (t & 7);
  #pragma unroll
  for (int m = 0; m < 32; ++m) r[m] = __half22float2(zs[PHY(base2 + (m<<3))]);
  dif_rec<32, 16>(r);
  twiddle_scale(r, (t & 7) << 5, false);
  #pragma unroll
  for (int m = 0; m < 32; ++m)
    zs[PHY(base2 + (m<<3))] = __floats2half2_rn(r[m].x, r[m].y);
  __syncthreads();

  // ---- phase 3: fwd spans 4,2,1 + MASK + inv spans 1,2,4 on {32t + e} ----
  #pragma unroll
  for (int e = 0; e < 32; ++e) r[e] = __half22float2(zs[PHY((t<<5) + e)]);
  #pragma unroll
  for (int g = 0; g < 4; ++g) dif_rec<8, 4>(r + 8*g);
  #pragma unroll
  for (int e = 0; e < 32; ++e){
    const int p  = (t << 5) + e;
    const int k  = (int)(__brev((unsigned)p) >> 19);   // brev13: p holds bin k
    const int kf = min(k, FFT_N - k);
    if (kf <= 819) r[e] = make_float2(0.f, 0.f);       // |freq| < 10 Hz
  }
  #pragma unroll
  for (int g = 0; g < 4; ++g) dit_rec<8, 1>(r + 8*g);
  #pragma unroll
  for (int e = 0; e < 32; ++e)
    zs[PHY((t<<5) + e)] = __floats2half2_rn(r[e].x, r[e].y);
  __syncthreads();

  // ---- inv phase 2: conj pre-twiddle, then DIT spans 8..128 ----
  #pragma unroll
  for (int m = 0; m < 32; ++m) r[m] = __half22float2(zs[PHY(base2 + (m<<3))]);
  twiddle_scale(r, (t & 7) << 5, true);
  dit_rec<32, 1>(r);
  #pragma unroll
  for (int m = 0; m < 32; ++m)
    zs[PHY(base2 + (m<<3))] = __floats2half2_rn(r[m].x, r[m].y);
  __syncthreads();

  // ---- inv phase 1: conj pre-twiddle, DIT spans 256..4096, store ----
  #pragma unroll
  for (int m = 0; m < 32; ++m) r[m] = __half22float2(zs[PHY(t + (m<<8))]);
  twiddle_scale(r, t, true);
  dit_rec<32, 1>(r);
  const float invn = 1.f / (float)FFT_N;
  float* o0 = out + pair * (2LL * FFT_N);
  float* o1 = o0 + FFT_N;
  #pragma unroll
  for (int m = 0; m < 32; ++m){
    const int n = t + (m << 8);
    __builtin_nontemporal_store(r[m].x * invn, o0 + n);
    __builtin_nontemporal_store(r[m].y * invn, o1 + n);
  }
}

extern "C" void kernel_launch(void* const* d_in, const int* in_sizes, int n_in,
                              void* d_out, int out_size, void* d_ws, size_t ws_size,
                              hipStream_t stream) {
  const float* x = (const float*)d_in[0];
  float* out = (float*)d_out;
  const int total  = in_sizes[0];              // 64*128*8192
  const int npairs = total / (2 * FFT_N);      // 4096 row pairs
  hipLaunchKernelGGL(fourier_filter_kernel, dim3(npairs), dim3(NT), 0, stream,
                     x, out);
}

// Round 5
// 133.246 us; speedup vs baseline: 1.1873x; 1.1873x over previous
//
#include <hip/hip_runtime.h>
#include <hip/hip_fp16.h>

// FourierFilter: out = Re(IFFT(mask * FFT(x, axis=-1))), mask zeroes bins with
// |freq| < 10 Hz (kf <= 819 of 8192 @ 100 Hz). x: [64,128,8192] f32.
//
// Register-resident four-step FFT. Two real rows packed into one complex row.
// 256 threads x 32 float2 regs. Radix-2 DIF stage spans decomposed 5+5+3:
//   phase1 (regs): spans 4096..256 on {c + 256m}  = const-twiddle FFT32 + post
//                  twiddle W_8192^{c*brev5(m)} (block-uniform deferral).
//   phase2 (regs): spans 128..8 on {256*blk + off3 + 8m}, c' = 32*off3.
//   phase3 (regs): contiguous FFT8s: fwd + MASK(brev13) + inv fused, no LDS.
//   inverse mirrors (conj pre-twiddle, then DIT).
// 4 LDS round-trips / 4 barriers (each thread's phase read-set == write-set).
//
// LDS intermediates in fp16 (__half2 packs re/im -> 4B/elem): 32.5 KB => 4
// blocks/CU. All phase lane-patterns are exactly 2 lanes/bank (free on wave64).
//
// R4 change (single variable): __launch_bounds__(256,2) — R3's (256,4) forced
// VGPR 128->64 and the 32 live float2 spilled into AGPR/scratch shuffle
// (VGPR_Count=64 + ~170MB extra WRITE traffic + dur regression). 128 VGPR
// still gives 4 waves/SIMD; LDS still admits 4 blocks/CU.

#define FFT_N 8192
#define NT    256
#define PHY(i) ((i) + ((i) >> 6))

__device__ __forceinline__ float2 cadd(float2 a, float2 b){ return make_float2(a.x+b.x, a.y+b.y); }
__device__ __forceinline__ float2 csub(float2 a, float2 b){ return make_float2(a.x-b.x, a.y-b.y); }
__device__ __forceinline__ float2 cmul(float2 a, float2 b){
    return make_float2(fmaf(a.x, b.x, -(a.y*b.y)), fmaf(a.x, b.y, a.y*b.x));
}

// d * W_32^j (or conj), j in [0,16), compile-time after unroll -> branches fold.
__device__ __forceinline__ float2 mul_w32(float2 d, int j, bool cj){
  if (j == 0) return d;
  if (j == 8) return cj ? make_float2(-d.y, d.x) : make_float2(d.y, -d.x);
  const float C[16] = {1.f, 0.98078528f, 0.92387953f, 0.83146961f, 0.70710678f,
                       0.55557023f, 0.38268343f, 0.19509032f, 0.f, -0.19509032f,
                       -0.38268343f, -0.55557023f, -0.70710678f, -0.83146961f,
                       -0.92387953f, -0.98078528f};
  const float S[16] = {0.f, -0.19509032f, -0.38268343f, -0.55557023f, -0.70710678f,
                       -0.83146961f, -0.92387953f, -0.98078528f, -1.f, -0.98078528f,
                       -0.92387953f, -0.83146961f, -0.70710678f, -0.55557023f,
                       -0.38268343f, -0.19509032f};
  return cmul(d, make_float2(C[j], cj ? -S[j] : S[j]));
}

// DIF radix-2 stages, spans L..1 over SZ regs. Twiddle W_SZ^{j*(SZ/2/L)} == W_32^{j*16/L}.
template<int SZ, int L>
__device__ __forceinline__ void dif_rec(float2* r){
  #pragma unroll
  for (int g = 0; g < SZ; g += 2*L){
    #pragma unroll
    for (int j = 0; j < L; ++j){
      float2 u = r[g+j], v = r[g+j+L];
      r[g+j]   = cadd(u, v);
      r[g+j+L] = mul_w32(csub(u, v), j*(16/L), false);
    }
  }
  if constexpr (L > 1) dif_rec<SZ, L/2>(r);
}

// Inverse DIT radix-2 stages, spans 1..SZ/2 (conjugate twiddles), unnormalized.
template<int SZ, int L>
__device__ __forceinline__ void dit_rec(float2* r){
  #pragma unroll
  for (int g = 0; g < SZ; g += 2*L){
    #pragma unroll
    for (int j = 0; j < L; ++j){
      float2 a = r[g+j];
      float2 b = mul_w32(r[g+j+L], j*(16/L), true);
      r[g+j]   = cadd(a, b);
      r[g+j+L] = csub(a, b);
    }
  }
  if constexpr (2*L < SZ) dit_rec<SZ, 2*L>(r);
}

__host__ __device__ constexpr int brev5(int k){
  return ((k&1)<<4) | ((k&2)<<2) | (k&4) | ((k&8)>>2) | ((k&16)>>4);
}

// r[brev5(k)] *= W_8192^{cbase*k} (or conj), k=1..31, via 1 sincos + power chain.
__device__ __forceinline__ void twiddle_scale(float2* r, int cbase, bool cj){
  float s, c;
  __sincosf((float)cbase * -7.6699039394282061e-4f, &s, &c);  // -2*pi/8192
  if (cj) s = -s;
  const float2 w1 = make_float2(c, s);
  float2 w = w1;
  r[brev5(1)] = cmul(r[brev5(1)], w);
  #pragma unroll
  for (int k = 2; k < 32; ++k){
    w = cmul(w, w1);
    r[brev5(k)] = cmul(r[brev5(k)], w);
  }
}

__global__ __launch_bounds__(NT, 2)
void fourier_filter_kernel(const float* __restrict__ x, float* __restrict__ out){
  __shared__ __half2 zs[FFT_N + FFT_N/64];   // 8320 * 4B = 32.5 KB (pad every 64)
  const int t = threadIdx.x;
  const long long pair = blockIdx.x;
  const float* r0 = x + pair * (2LL * FFT_N);
  const float* r1 = r0 + FFT_N;
  float2 r[32];

  // ---- fwd phase 1: spans 4096..256 on {t + 256m} (coalesced global load) ----
  #pragma unroll
  for (int m = 0; m < 32; ++m){
    const int n = t + (m << 8);
    r[m] = make_float2(__builtin_nontemporal_load(r0 + n),
                       __builtin_nontemporal_load(r1 + n));
  }
  dif_rec<32, 16>(r);
  twiddle_scale(r, t, false);
  #pragma unroll
  for (int m = 0; m < 32; ++m)
    zs[PHY(t + (m<<8))] = __floats2half2_rn(r[m].x, r[m].y);
  __syncthreads();

  // ---- fwd phase 2: spans 128..8 on {256*(t>>3) + (t&7) + 8m} ----
  const int base2 = ((t >> 3) << 8) | (t & 7);
  #pragma unroll
  for (int m = 0; m < 32; ++m) r[m] = __half22float2(zs[PHY(base2 + (m<<3))]);
  dif_rec<32, 16>(r);
  twiddle_scale(r, (t & 7) << 5, false);
  #pragma unroll
  for (int m = 0; m < 32; ++m)
    zs[PHY(base2 + (m<<3))] = __floats2half2_rn(r[m].x, r[m].y);
  __syncthreads();

  // ---- phase 3: fwd spans 4,2,1 + MASK + inv spans 1,2,4 on {32t + e} ----
  #pragma unroll
  for (int e = 0; e < 32; ++e) r[e] = __half22float2(zs[PHY((t<<5) + e)]);
  #pragma unroll
  for (int g = 0; g < 4; ++g) dif_rec<8, 4>(r + 8*g);
  #pragma unroll
  for (int e = 0; e < 32; ++e){
    const int p  = (t << 5) + e;
    const int k  = (int)(__brev((unsigned)p) >> 19);   // brev13: p holds bin k
    const int kf = min(k, FFT_N - k);
    if (kf <= 819) r[e] = make_float2(0.f, 0.f);       // |freq| < 10 Hz
  }
  #pragma unroll
  for (int g = 0; g < 4; ++g) dit_rec<8, 1>(r + 8*g);
  #pragma unroll
  for (int e = 0; e < 32; ++e)
    zs[PHY((t<<5) + e)] = __floats2half2_rn(r[e].x, r[e].y);
  __syncthreads();

  // ---- inv phase 2: conj pre-twiddle, then DIT spans 8..128 ----
  #pragma unroll
  for (int m = 0; m < 32; ++m) r[m] = __half22float2(zs[PHY(base2 + (m<<3))]);
  twiddle_scale(r, (t & 7) << 5, true);
  dit_rec<32, 1>(r);
  #pragma unroll
  for (int m = 0; m < 32; ++m)
    zs[PHY(base2 + (m<<3))] = __floats2half2_rn(r[m].x, r[m].y);
  __syncthreads();

  // ---- inv phase 1: conj pre-twiddle, DIT spans 256..4096, store ----
  #pragma unroll
  for (int m = 0; m < 32; ++m) r[m] = __half22float2(zs[PHY(t + (m<<8))]);
  twiddle_scale(r, t, true);
  dit_rec<32, 1>(r);
  const float invn = 1.f / (float)FFT_N;
  float* o0 = out + pair * (2LL * FFT_N);
  float* o1 = o0 + FFT_N;
  #pragma unroll
  for (int m = 0; m < 32; ++m){
    const int n = t + (m << 8);
    __builtin_nontemporal_store(r[m].x * invn, o0 + n);
    __builtin_nontemporal_store(r[m].y * invn, o1 + n);
  }
}

extern "C" void kernel_launch(void* const* d_in, const int* in_sizes, int n_in,
                              void* d_out, int out_size, void* d_ws, size_t ws_size,
                              hipStream_t stream) {
  const float* x = (const float*)d_in[0];
  float* out = (float*)d_out;
  const int total  = in_sizes[0];              // 64*128*8192
  const int npairs = total / (2 * FFT_N);      // 4096 row pairs
  hipLaunchKernelGGL(fourier_filter_kernel, dim3(npairs), dim3(NT), 0, stream,
                     x, out);
}

// Round 6
// 122.764 us; speedup vs baseline: 1.2887x; 1.0854x over previous
//
#include <hip/hip_runtime.h>
#include <hip/hip_fp16.h>

// FourierFilter: out = Re(IFFT(mask * FFT(x, axis=-1))), mask zeroes bins with
// |freq| < 10 Hz (kf <= 819 of 8192 @ 100 Hz). x: [64,128,8192] f32.
//
// Register-resident four-step FFT. Two real rows packed into one complex row.
// 256 threads x 32 complex regs. Radix-2 DIF spans decomposed 5+5+3 (phase1
// spans 4096..256 on {t+256m} w/ deferred twiddle W^{t*brev5(m)}; phase2 spans
// 128..8 on {256*(t>>3)+(t&7)+8m}; phase3 contiguous FFT8 fwd+MASK+inv fused;
// inverse mirrors). 4 LDS round-trips / 4 barriers. LDS in fp16 (__half2,
// 32.5 KB, pad n+(n>>6): all patterns 2 lanes/bank = free on wave64).
//
// R5 change: complex type = ext_vector_type(2) float so the backend forms
// packed fp32 VALU (v_pk_add_f32 / v_pk_fma_f32, VOP3P): cadd/csub 2->1 instr,
// cmul 4->2. Twiddle power chain split into two half-length chains via
// w16 = w1^16 (repeated squaring): same ops, half the serial depth.

#define FFT_N 8192
#define NT    256
#define PHY(i) ((i) + ((i) >> 6))

typedef float v2f __attribute__((ext_vector_type(2)));

__device__ __forceinline__ v2f cmul(v2f a, v2f b){
  // (a.x*b.x - a.y*b.y, a.x*b.y + a.y*b.x) = a.xx * b + a.yy * (-b.y, b.x)
  v2f axx = {a.x, a.x};
  v2f ayy = {a.y, a.y};
  v2f byx = {-b.y, b.x};
  return axx * b + ayy * byx;
}

// d * W_32^j (or conj), j in [0,16), compile-time after unroll -> constants fold.
__device__ __forceinline__ v2f mul_w32(v2f d, int j, bool cj){
  if (j == 0) return d;
  if (j == 8) return cj ? (v2f){-d.y, d.x} : (v2f){d.y, -d.x};
  const float C[16] = {1.f, 0.98078528f, 0.92387953f, 0.83146961f, 0.70710678f,
                       0.55557023f, 0.38268343f, 0.19509032f, 0.f, -0.19509032f,
                       -0.38268343f, -0.55557023f, -0.70710678f, -0.83146961f,
                       -0.92387953f, -0.98078528f};
  const float S[16] = {0.f, -0.19509032f, -0.38268343f, -0.55557023f, -0.70710678f,
                       -0.83146961f, -0.92387953f, -0.98078528f, -1.f, -0.98078528f,
                       -0.92387953f, -0.83146961f, -0.70710678f, -0.55557023f,
                       -0.38268343f, -0.19509032f};
  v2f w = {C[j], cj ? -S[j] : S[j]};
  return cmul(d, w);
}

// DIF radix-2 stages, spans L..1 over SZ regs. Twiddle W_SZ^{j*(SZ/2/L)} == W_32^{j*16/L}.
template<int SZ, int L>
__device__ __forceinline__ void dif_rec(v2f* r){
  #pragma unroll
  for (int g = 0; g < SZ; g += 2*L){
    #pragma unroll
    for (int j = 0; j < L; ++j){
      v2f u = r[g+j], v = r[g+j+L];
      r[g+j]   = u + v;
      r[g+j+L] = mul_w32(u - v, j*(16/L), false);
    }
  }
  if constexpr (L > 1) dif_rec<SZ, L/2>(r);
}

// Inverse DIT radix-2 stages, spans 1..SZ/2 (conjugate twiddles), unnormalized.
template<int SZ, int L>
__device__ __forceinline__ void dit_rec(v2f* r){
  #pragma unroll
  for (int g = 0; g < SZ; g += 2*L){
    #pragma unroll
    for (int j = 0; j < L; ++j){
      v2f a = r[g+j];
      v2f b = mul_w32(r[g+j+L], j*(16/L), true);
      r[g+j]   = a + b;
      r[g+j+L] = a - b;
    }
  }
  if constexpr (2*L < SZ) dit_rec<SZ, 2*L>(r);
}

__host__ __device__ constexpr int brev5(int k){
  return ((k&1)<<4) | ((k&2)<<2) | (k&4) | ((k&8)>>2) | ((k&16)>>4);
}

// r[brev5(k)] *= W_8192^{cbase*k} (or conj), k=1..31.
// Two half-length chains (k=1..15 and k+16 = w16 * w^k) for 2x ILP, half depth.
__device__ __forceinline__ void twiddle_scale(v2f* r, int cbase, bool cj){
  float s, c;
  __sincosf((float)cbase * -7.6699039394282061e-4f, &s, &c);  // -2*pi/8192
  if (cj) s = -s;
  const v2f w1 = {c, s};
  v2f w2q = cmul(w1, w1);
  v2f w4q = cmul(w2q, w2q);
  v2f w8q = cmul(w4q, w4q);
  v2f w16 = cmul(w8q, w8q);
  v2f wa = w1;
  r[brev5(1)]  = cmul(r[brev5(1)],  wa);
  r[brev5(17)] = cmul(r[brev5(17)], cmul(w16, wa));
  #pragma unroll
  for (int k = 2; k <= 15; ++k){
    wa = cmul(wa, w1);
    r[brev5(k)]    = cmul(r[brev5(k)],    wa);
    r[brev5(k+16)] = cmul(r[brev5(k+16)], cmul(w16, wa));
  }
  r[brev5(16)] = cmul(r[brev5(16)], w16);
}

__global__ __launch_bounds__(NT, 2)
void fourier_filter_kernel(const float* __restrict__ x, float* __restrict__ out){
  __shared__ __half2 zs[FFT_N + FFT_N/64];   // 8320 * 4B = 32.5 KB (pad every 64)
  const int t = threadIdx.x;
  const long long pair = blockIdx.x;
  const float* r0 = x + pair * (2LL * FFT_N);
  const float* r1 = r0 + FFT_N;
  v2f r[32];

  // ---- fwd phase 1: spans 4096..256 on {t + 256m} (coalesced global load) ----
  #pragma unroll
  for (int m = 0; m < 32; ++m){
    const int n = t + (m << 8);
    r[m] = (v2f){__builtin_nontemporal_load(r0 + n),
                 __builtin_nontemporal_load(r1 + n)};
  }
  dif_rec<32, 16>(r);
  twiddle_scale(r, t, false);
  #pragma unroll
  for (int m = 0; m < 32; ++m)
    zs[PHY(t + (m<<8))] = __floats2half2_rn(r[m].x, r[m].y);
  __syncthreads();

  // ---- fwd phase 2: spans 128..8 on {256*(t>>3) + (t&7) + 8m} ----
  const int base2 = ((t >> 3) << 8) | (t & 7);
  #pragma unroll
  for (int m = 0; m < 32; ++m){
    float2 f = __half22float2(zs[PHY(base2 + (m<<3))]);
    r[m] = (v2f){f.x, f.y};
  }
  dif_rec<32, 16>(r);
  twiddle_scale(r, (t & 7) << 5, false);
  #pragma unroll
  for (int m = 0; m < 32; ++m)
    zs[PHY(base2 + (m<<3))] = __floats2half2_rn(r[m].x, r[m].y);
  __syncthreads();

  // ---- phase 3: fwd spans 4,2,1 + MASK + inv spans 1,2,4 on {32t + e} ----
  #pragma unroll
  for (int e = 0; e < 32; ++e){
    float2 f = __half22float2(zs[PHY((t<<5) + e)]);
    r[e] = (v2f){f.x, f.y};
  }
  #pragma unroll
  for (int g = 0; g < 4; ++g) dif_rec<8, 4>(r + 8*g);
  #pragma unroll
  for (int e = 0; e < 32; ++e){
    const int p  = (t << 5) + e;
    const int k  = (int)(__brev((unsigned)p) >> 19);   // brev13: p holds bin k
    const int kf = min(k, FFT_N - k);
    if (kf <= 819) r[e] = (v2f){0.f, 0.f};             // |freq| < 10 Hz
  }
  #pragma unroll
  for (int g = 0; g < 4; ++g) dit_rec<8, 1>(r + 8*g);
  #pragma unroll
  for (int e = 0; e < 32; ++e)
    zs[PHY((t<<5) + e)] = __floats2half2_rn(r[e].x, r[e].y);
  __syncthreads();

  // ---- inv phase 2: conj pre-twiddle, then DIT spans 8..128 ----
  #pragma unroll
  for (int m = 0; m < 32; ++m){
    float2 f = __half22float2(zs[PHY(base2 + (m<<3))]);
    r[m] = (v2f){f.x, f.y};
  }
  twiddle_scale(r, (t & 7) << 5, true);
  dit_rec<32, 1>(r);
  #pragma unroll
  for (int m = 0; m < 32; ++m)
    zs[PHY(base2 + (m<<3))] = __floats2half2_rn(r[m].x, r[m].y);
  __syncthreads();

  // ---- inv phase 1: conj pre-twiddle, DIT spans 256..4096, store ----
  #pragma unroll
  for (int m = 0; m < 32; ++m){
    float2 f = __half22float2(zs[PHY(t + (m<<8))]);
    r[m] = (v2f){f.x, f.y};
  }
  twiddle_scale(r, t, true);
  dit_rec<32, 1>(r);
  const float invn = 1.f / (float)FFT_N;
  float* o0 = out + pair * (2LL * FFT_N);
  float* o1 = o0 + FFT_N;
  #pragma unroll
  for (int m = 0; m < 32; ++m){
    const int n = t + (m << 8);
    __builtin_nontemporal_store(r[m].x * invn, o0 + n);
    __builtin_nontemporal_store(r[m].y * invn, o1 + n);
  }
}

extern "C" void kernel_launch(void* const* d_in, const int* in_sizes, int n_in,
                              void* d_out, int out_size, void* d_ws, size_t ws_size,
                              hipStream_t stream) {
  const float* x = (const float*)d_in[0];
  float* out = (float*)d_out;
  const int total  = in_sizes[0];              // 64*128*8192
  const int npairs = total / (2 * FFT_N);      // 4096 row pairs
  hipLaunchKernelGGL(fourier_filter_kernel, dim3(npairs), dim3(NT), 0, stream,
                     x, out);
}